// Round 6
// baseline (407.358 us; speedup 1.0000x reference)
//
#include <hip/hip_runtime.h>
#include <cstdint>

#define M_DIM 8192   // B*S = 4*2048
#define N_DIM 4096   // D_OUT
#define K_DIM 4096   // D_IN
#define NT    32     // K_DIM / 128 K-tiles

typedef int i32x4 __attribute__((ext_vector_type(4)));

// async global->LDS, 16B per lane. LDS dest is wave-uniform base; HW
// scatters lane i to base + i*16. Global source IS per-lane (swizzle there).
__device__ __forceinline__ void gload_lds16(const void* g, void* l) {
  __builtin_amdgcn_global_load_lds(
      (const __attribute__((address_space(1))) unsigned int*)(uintptr_t)g,
      (__attribute__((address_space(3))) unsigned int*)(uintptr_t)l,
      16, 0, 0);
}

// ---------------- prep (unchanged) ----------------
__global__ __launch_bounds__(256) void prep_kernel(
    const float* __restrict__ x, const int* __restrict__ q,
    signed char* __restrict__ xq, signed char* __restrict__ wq8,
    float* __restrict__ sx, float* __restrict__ si) {
  const int tid  = threadIdx.x;
  const int lane = tid & 63;
  const int wv   = tid >> 6;
  if (blockIdx.x < 2048) {
    const int row = blockIdx.x * 4 + wv;
    const float* xr = x + (size_t)row * K_DIM;
    signed char* xo = xq + (size_t)row * K_DIM;
    float4 v[16];
    float amax = 0.f;
#pragma unroll
    for (int j = 0; j < 16; ++j) {
      v[j] = *(const float4*)(xr + j * 256 + lane * 4);
      amax = fmaxf(amax, fmaxf(fmaxf(fabsf(v[j].x), fabsf(v[j].y)),
                               fmaxf(fabsf(v[j].z), fabsf(v[j].w))));
    }
#pragma unroll
    for (int off = 32; off > 0; off >>= 1)
      amax = fmaxf(amax, __shfl_xor(amax, off, 64));
    const float inv = amax > 0.f ? 127.f / amax : 0.f;
    int isum = 0;
#pragma unroll
    for (int j = 0; j < 16; ++j) {
      int ix = __float2int_rn(v[j].x * inv);
      int iy = __float2int_rn(v[j].y * inv);
      int iz = __float2int_rn(v[j].z * inv);
      int iw = __float2int_rn(v[j].w * inv);
      isum += ix + iy + iz + iw;
      char4 o; o.x = (char)ix; o.y = (char)iy; o.z = (char)iz; o.w = (char)iw;
      *(char4*)(xo + j * 256 + lane * 4) = o;
    }
#pragma unroll
    for (int off = 32; off > 0; off >>= 1)
      isum += __shfl_xor(isum, off, 64);
    if (lane == 0) {
      sx[row] = amax * (1.f / 127.f);
      si[row] = (float)isum;
    }
  } else {
    const int bid = blockIdx.x - 2048;               // 0..1023
    const size_t total  = (size_t)N_DIM * K_DIM;     // 16.78M ints
    const size_t stride = (size_t)1024 * 4096;       // ints per sweep
    for (size_t base = (size_t)bid * 4096; base < total; base += stride) {
#pragma unroll
      for (int u = 0; u < 4; ++u) {
        const size_t idx = base + (size_t)u * 1024 + tid * 4;
        int4 w = *(const int4*)(q + idx);
        char4 o; o.x = (char)w.x; o.y = (char)w.y; o.z = (char)w.z; o.w = (char)w.w;
        *(char4*)(wq8 + idx) = o;
      }
    }
  }
}

// ---------------- GEMM i8, 128x128 tile, BK=128, 4 waves, 64KB LDS -------
// r1's proven 4-phase schedule shrunk so TWO blocks co-reside per CU
// (64KB LDS each; 128KB <= 160KB). Two independent barrier groups break the
// all-waves-lockstep that kept LDS reads and MFMA serial (r1-r4 all measured
// ~= MFMA_cyc + LDS_cyc per tile). Same wave count per CU (8), same 16x16
// MFMA + XOR swizzle (measured 0 bank conflicts), same vmcnt ledger.
//
// Staging: 8 stages of 32 rows each per tile. Issue order per tile:
//   B0,B1,B2,B3 (B rows 0-127), A0,A2 (A rows 0-31,64-95), A1,A3 (32-63,96-127)
// Ledger: entry 8 outstanding. ph1 vmcnt(2): B all + A0,A2 landed (covers
// each wave's m-subtiles 0-1). ph3 vmcnt(4): A1,A3 landed (m-subtiles 2-3).
// Never drains to 0 mid-loop. Stages target buf^1, whose last reads
// completed >=2 barriers earlier.
__global__ __launch_bounds__(256) void qlinear_gemm_kernel(
    const signed char* __restrict__ A,     // [M][K] int8
    const signed char* __restrict__ Bm,    // [N][K] int8
    const float* __restrict__ sx,          // [M]
    const float* __restrict__ si,          // [M]
    const float* __restrict__ scale_p, const float* __restrict__ zp_p,
    const float* __restrict__ bias,        // [N]
    float* __restrict__ out) {             // [M][N] fp32
  __shared__ signed char sA[2][16384];     // 32 KB: 128 rows x 128 B, dbuf
  __shared__ signed char sB[2][16384];     // 32 KB

  const int tid  = threadIdx.x;
  const int lane = tid & 63;
  const int w    = tid >> 6;     // wave 0..3
  const int wr   = w >> 1;       // 0..1 : wave row (M), rows wr*64..+63
  const int wc   = w & 1;        // 0..1 : wave col (N), cols wc*64..+63
  const int lr   = lane & 15;
  const int quad = lane >> 4;

  const int bm = blockIdx.y * 128;
  const int bn = blockIdx.x * 128;

  // ---- staging: per-lane pre-swizzled global source ----
  const int srow = lane >> 3;              // row within 8-row wave slab
  const int cg   = (lane & 7) ^ srow;      // global 16B chunk for this lane
  const signed char* aG = A  + (size_t)(bm + w * 8 + srow) * K_DIM + cg * 16;
  const signed char* bG = Bm + (size_t)(bn + w * 8 + srow) * K_DIM + cg * 16;
  const int dwoff = w * 1024;              // wave-uniform LDS slab offset

  // stage c covers tile rows c*32 + w*8 + srow; LDS linear row*128
#define STG_A(dst, c, t) \
  gload_lds16(aG + (size_t)((c) * 32) * K_DIM + (size_t)(t) * 128, \
              (dst) + (c) * 4096 + dwoff)
#define STG_B(dst, c, t) \
  gload_lds16(bG + (size_t)((c) * 32) * K_DIM + (size_t)(t) * 128, \
              (dst) + (c) * 4096 + dwoff)

  // read-side swizzled byte offsets per k-substep (16x16 pattern, 0-conflict)
  int off[2];
#pragma unroll
  for (int ks = 0; ks < 2; ++ks)
    off[ks] = lr * 128 + (((ks * 4 + quad) ^ (lr & 7)) * 16);

  i32x4 acc[4][4] = {};

  // ---- prologue: stage tile 0 in steady-state issue order ----
  {
    signed char* dA = &sA[0][0];
    signed char* dB = &sB[0][0];
    STG_B(dB, 0, 0); STG_B(dB, 1, 0); STG_B(dB, 2, 0); STG_B(dB, 3, 0);
    STG_A(dA, 0, 0); STG_A(dA, 2, 0);
    STG_A(dA, 1, 0); STG_A(dA, 3, 0);
  }

  for (int t = 0; t < NT; ++t) {
    const int buf = t & 1;
    const signed char* pA = &sA[buf][0] + wr * 8192;   // wave's 64 A-rows
    const signed char* pB = &sB[buf][0] + wc * 8192;   // wave's 64 B-rows
    signed char* nA = &sA[buf ^ 1][0];
    signed char* nB = &sB[buf ^ 1][0];
    const bool st = (t + 1) < NT;
    const int tn = t + 1;

    i32x4 afr[2][2], afr2[2][2], bfr0[2][2], bfr1[2][2];

    // ---------- phase 1 : m0-1 x n0-1 ----------
    asm volatile("s_waitcnt vmcnt(2)" ::: "memory");   // B*4 + A0,A2 landed
    if (st) { STG_B(nB, 0, tn); STG_B(nB, 1, tn); }
    __builtin_amdgcn_s_barrier();
#pragma unroll
    for (int m = 0; m < 2; ++m)
#pragma unroll
      for (int ks = 0; ks < 2; ++ks)
        afr[m][ks] = *(const i32x4*)(pA + m * 2048 + off[ks]);
#pragma unroll
    for (int n = 0; n < 2; ++n)
#pragma unroll
      for (int ks = 0; ks < 2; ++ks)
        bfr0[n][ks] = *(const i32x4*)(pB + n * 2048 + off[ks]);
    __builtin_amdgcn_s_setprio(1);
#pragma unroll
    for (int m = 0; m < 2; ++m)
#pragma unroll
      for (int n = 0; n < 2; ++n)
#pragma unroll
        for (int ks = 0; ks < 2; ++ks)
          acc[m][n] = __builtin_amdgcn_mfma_i32_16x16x64_i8(
              afr[m][ks], bfr0[n][ks], acc[m][n], 0, 0, 0);
    __builtin_amdgcn_s_setprio(0);

    // ---------- phase 2 : m0-1 x n2-3 ----------
    if (st) { STG_B(nB, 2, tn); STG_B(nB, 3, tn); }
    __builtin_amdgcn_s_barrier();
#pragma unroll
    for (int n = 0; n < 2; ++n)
#pragma unroll
      for (int ks = 0; ks < 2; ++ks)
        bfr1[n][ks] = *(const i32x4*)(pB + 4096 + n * 2048 + off[ks]);
    __builtin_amdgcn_s_setprio(1);
#pragma unroll
    for (int m = 0; m < 2; ++m)
#pragma unroll
      for (int n = 0; n < 2; ++n)
#pragma unroll
        for (int ks = 0; ks < 2; ++ks)
          acc[m][2 + n] = __builtin_amdgcn_mfma_i32_16x16x64_i8(
              afr[m][ks], bfr1[n][ks], acc[m][2 + n], 0, 0, 0);
    __builtin_amdgcn_s_setprio(0);

    // ---------- phase 3 : m2-3 x n0-1 ----------
    if (st) asm volatile("s_waitcnt vmcnt(4)" ::: "memory");  // A1,A3 landed
    else    asm volatile("s_waitcnt vmcnt(0)" ::: "memory");  // last tile drain
    if (st) { STG_A(nA, 0, tn); STG_A(nA, 2, tn); }
    __builtin_amdgcn_s_barrier();
#pragma unroll
    for (int m = 0; m < 2; ++m)
#pragma unroll
      for (int ks = 0; ks < 2; ++ks)
        afr2[m][ks] = *(const i32x4*)(pA + 4096 + m * 2048 + off[ks]);
    __builtin_amdgcn_s_setprio(1);
#pragma unroll
    for (int m = 0; m < 2; ++m)
#pragma unroll
      for (int n = 0; n < 2; ++n)
#pragma unroll
        for (int ks = 0; ks < 2; ++ks)
          acc[2 + m][n] = __builtin_amdgcn_mfma_i32_16x16x64_i8(
              afr2[m][ks], bfr0[n][ks], acc[2 + m][n], 0, 0, 0);
    __builtin_amdgcn_s_setprio(0);

    // ---------- phase 4 : m2-3 x n2-3 ----------
    if (st) { STG_A(nA, 1, tn); STG_A(nA, 3, tn); }
    __builtin_amdgcn_s_barrier();
    __builtin_amdgcn_s_setprio(1);
#pragma unroll
    for (int m = 0; m < 2; ++m)
#pragma unroll
      for (int n = 0; n < 2; ++n)
#pragma unroll
        for (int ks = 0; ks < 2; ++ks)
          acc[2 + m][2 + n] = __builtin_amdgcn_mfma_i32_16x16x64_i8(
              afr2[m][ks], bfr1[n][ks], acc[2 + m][2 + n], 0, 0, 0);
    __builtin_amdgcn_s_setprio(0);
  }
#undef STG_A
#undef STG_B

  // ---------- epilogue ----------
  const float scale = *scale_p;
  const float zp    = *zp_p;
  // C/D layout: col = lane&15, row = quad*4 + reg (dtype-independent)
#pragma unroll
  for (int i = 0; i < 4; ++i) {
    const int gm0 = bm + wr * 64 + i * 16 + quad * 4;
    float am[4], cm[4];
#pragma unroll
    for (int r = 0; r < 4; ++r) {
      am[r] = scale * sx[gm0 + r];
      cm[r] = -am[r] * zp * si[gm0 + r];
    }
#pragma unroll
    for (int j = 0; j < 4; ++j) {
      const int gn = bn + wc * 64 + j * 16 + lr;
      const float bb = bias[gn];
#pragma unroll
      for (int r = 0; r < 4; ++r)
        out[(size_t)(gm0 + r) * N_DIM + gn] =
            am[r] * (float)acc[i][j][r] + cm[r] + bb;
    }
  }
}

extern "C" void kernel_launch(void* const* d_in, const int* in_sizes, int n_in,
                              void* d_out, int out_size, void* d_ws, size_t ws_size,
                              hipStream_t stream) {
  const float* x     = (const float*)d_in[0];
  const int*   wq    = (const int*)d_in[1];
  const float* scale = (const float*)d_in[2];
  const float* zp    = (const float*)d_in[3];
  const float* bias  = (const float*)d_in[4];
  float* out = (float*)d_out;

  // ws: xq (8192*4096 i8) | wq8 (4096*4096 i8) | sx | si
  signed char* xq  = (signed char*)d_ws;
  signed char* wq8 = xq + (size_t)M_DIM * K_DIM;
  float* sx = (float*)(wq8 + (size_t)N_DIM * K_DIM);
  float* si = sx + M_DIM;

  prep_kernel<<<3072, 256, 0, stream>>>(x, wq, xq, wq8, sx, si);
  dim3 grid(N_DIM / 128, M_DIM / 128);  // 32 x 64
  qlinear_gemm_kernel<<<grid, 256, 0, stream>>>(xq, wq8, sx, si, scale, zp, bias, out);
}

// Round 7
// 382.626 us; speedup vs baseline: 1.0646x; 1.0646x over previous
//
#include <hip/hip_runtime.h>
#include <cstdint>

#define M_DIM 8192   // B*S = 4*2048
#define N_DIM 4096   // D_OUT
#define K_DIM 4096   // D_IN
#define NT    32     // K_DIM / 128 K-tiles

typedef int i32x4 __attribute__((ext_vector_type(4)));

// async global->LDS, 16B per lane. LDS dest is wave-uniform base; HW
// scatters lane i to base + i*16. Global source IS per-lane (swizzle there).
__device__ __forceinline__ void gload_lds16(const void* g, void* l) {
  __builtin_amdgcn_global_load_lds(
      (const __attribute__((address_space(1))) unsigned int*)(uintptr_t)g,
      (__attribute__((address_space(3))) unsigned int*)(uintptr_t)l,
      16, 0, 0);
}

// ---------------- prep (unchanged) ----------------
__global__ __launch_bounds__(256) void prep_kernel(
    const float* __restrict__ x, const int* __restrict__ q,
    signed char* __restrict__ xq, signed char* __restrict__ wq8,
    float* __restrict__ sx, float* __restrict__ si) {
  const int tid  = threadIdx.x;
  const int lane = tid & 63;
  const int wv   = tid >> 6;
  if (blockIdx.x < 2048) {
    const int row = blockIdx.x * 4 + wv;
    const float* xr = x + (size_t)row * K_DIM;
    signed char* xo = xq + (size_t)row * K_DIM;
    float4 v[16];
    float amax = 0.f;
#pragma unroll
    for (int j = 0; j < 16; ++j) {
      v[j] = *(const float4*)(xr + j * 256 + lane * 4);
      amax = fmaxf(amax, fmaxf(fmaxf(fabsf(v[j].x), fabsf(v[j].y)),
                               fmaxf(fabsf(v[j].z), fabsf(v[j].w))));
    }
#pragma unroll
    for (int off = 32; off > 0; off >>= 1)
      amax = fmaxf(amax, __shfl_xor(amax, off, 64));
    const float inv = amax > 0.f ? 127.f / amax : 0.f;
    int isum = 0;
#pragma unroll
    for (int j = 0; j < 16; ++j) {
      int ix = __float2int_rn(v[j].x * inv);
      int iy = __float2int_rn(v[j].y * inv);
      int iz = __float2int_rn(v[j].z * inv);
      int iw = __float2int_rn(v[j].w * inv);
      isum += ix + iy + iz + iw;
      char4 o; o.x = (char)ix; o.y = (char)iy; o.z = (char)iz; o.w = (char)iw;
      *(char4*)(xo + j * 256 + lane * 4) = o;
    }
#pragma unroll
    for (int off = 32; off > 0; off >>= 1)
      isum += __shfl_xor(isum, off, 64);
    if (lane == 0) {
      sx[row] = amax * (1.f / 127.f);
      si[row] = (float)isum;
    }
  } else {
    const int bid = blockIdx.x - 2048;               // 0..1023
    const size_t total  = (size_t)N_DIM * K_DIM;     // 16.78M ints
    const size_t stride = (size_t)1024 * 4096;       // ints per sweep
    for (size_t base = (size_t)bid * 4096; base < total; base += stride) {
#pragma unroll
      for (int u = 0; u < 4; ++u) {
        const size_t idx = base + (size_t)u * 1024 + tid * 4;
        int4 w = *(const int4*)(q + idx);
        char4 o; o.x = (char)w.x; o.y = (char)w.y; o.z = (char)w.z; o.w = (char)w.w;
        *(char4*)(wq8 + idx) = o;
      }
    }
  }
}

// ---------------- GEMM i8, 256x256, BK=128, 8 waves, 8-PHASE fine interleave
// Each K-tile split into 8 phases of 8 MFMAs (quadrant x k-substep).
// Per phase: [ds_read this phase's new frags] [stage 1 half-tile for t+1]
// [counted vmcnt at ph2/ph8 only] [s_barrier] [setprio1; 8 MFMA; setprio0].
// Reads issue BEFORE the barrier -> they drain during barrier-wait and
// stagger against other waves' MFMA tails (m196/m201 mechanism). No manual
// lgkmcnt (compiler inserts fine-grained waits); no sched_barrier pins.
//
// Ledger (stage order per tile: B00,B01,B10,B11,A00,A10,A01,A11; one/phase):
//   tile-entry queue = [A01,A11] of t.
//   ph2: after staging B01' queue=[A01,A11,B00',B01'] -> vmcnt(2) lands
//        A01,A11 (rows 64-127,192-255) needed by ph3/ph7 reads; ph2's
//        barrier collectivizes before ph3 reads.
//   ph8: after staging A11' queue=8 -> vmcnt(2) lands B*4+A00,A10 of t+1,
//        needed by ph1/ph2 of t+1; ph8's barrier collectivizes.
//   Never 0 mid-loop; last tile (no stages): vmcnt(0) at ph2 once.
// WAR: stage into buf^1 region R issues only after the barrier following the
// last reads of R (>=1 barrier earlier); barrier release proves all waves'
// reads retired (reads are consumed by pre-barrier MFMAs).
__global__ __launch_bounds__(512, 2) void qlinear_gemm_kernel(
    const signed char* __restrict__ A,     // [M][K] int8
    const signed char* __restrict__ Bm,    // [N][K] int8
    const float* __restrict__ sx,          // [M]
    const float* __restrict__ si,          // [M]
    const float* __restrict__ scale_p, const float* __restrict__ zp_p,
    const float* __restrict__ bias,        // [N]
    float* __restrict__ out) {             // [M][N] fp32
  __shared__ signed char sA[2][2][16384];  // 64 KB
  __shared__ signed char sB[2][2][16384];  // 64 KB

  const int tid  = threadIdx.x;
  const int lane = tid & 63;
  const int w    = tid >> 6;     // wave 0..7
  const int wr   = w >> 2;       // 0..1 : wave row (M), owns A-half wr
  const int wc   = w & 3;        // 0..3 : wave col (N)
  const int lr   = lane & 15;
  const int quad = lane >> 4;

  const int bm = blockIdx.y * 256;
  const int bn = blockIdx.x * 256;

  // ---- staging: per-lane pre-swizzled global source ----
  const int srow = lane >> 3;              // row within 8-row wave slab
  const int cg   = (lane & 7) ^ srow;      // global 16B chunk for this lane
  const signed char* aG = A  + (size_t)(bm + w * 8 + srow) * K_DIM + cg * 16;
  const signed char* bG = Bm + (size_t)(bn + w * 8 + srow) * K_DIM + cg * 16;
  const int dwoff = w * 1024;              // wave-uniform LDS slab offset

#define STG_A(dst, h, c, t) \
  gload_lds16(aG + (size_t)((h) * 128 + (c) * 64) * K_DIM + (size_t)(t) * 128, \
              (dst) + (h) * 16384 + (c) * 8192 + dwoff)
#define STG_B(dst, h, c, t) \
  gload_lds16(bG + (size_t)((h) * 128 + (c) * 64) * K_DIM + (size_t)(t) * 128, \
              (dst) + (h) * 16384 + (c) * 8192 + dwoff)

  // read-side swizzled byte offsets per k-substep (proven 0-conflict)
  int off[2];
#pragma unroll
  for (int ks = 0; ks < 2; ++ks)
    off[ks] = lr * 128 + (((ks * 4 + quad) ^ (lr & 7)) * 16);

  i32x4 acc[8][4] = {};
  i32x4 afrA[4], afrB[4], bfr0[2], bfr1[2];  // current-ks fragments

  // ---- prologue: stage tile 0 (steady-state order), collectivize ----
  {
    signed char* dA = &sA[0][0][0];
    signed char* dB = &sB[0][0][0];
    STG_B(dB, 0, 0, 0); STG_B(dB, 0, 1, 0);
    STG_B(dB, 1, 0, 0); STG_B(dB, 1, 1, 0);
    STG_A(dA, 0, 0, 0); STG_A(dA, 1, 0, 0);
    STG_A(dA, 0, 1, 0); STG_A(dA, 1, 1, 0);
  }
  asm volatile("s_waitcnt vmcnt(2)" ::: "memory");  // B*4 + A00,A10 landed
  __builtin_amdgcn_s_barrier();

  for (int t = 0; t < NT; ++t) {
    const int buf = t & 1;
    const signed char* pA = &sA[buf][wr][0];
    const signed char* pB = &sB[buf][wc >> 1][0] + (wc & 1) * 8192;
    signed char* nA = &sA[buf ^ 1][0][0];
    signed char* nB = &sB[buf ^ 1][0][0];
    const bool st = (t + 1) < NT;
    const int tn = t + 1;

#define MFMA8(AF, BF, MB, NB)                                              \
  __builtin_amdgcn_s_setprio(1);                                           \
  _Pragma("unroll")                                                        \
  for (int m = 0; m < 4; ++m)                                              \
    _Pragma("unroll")                                                      \
    for (int n = 0; n < 2; ++n)                                            \
      acc[(MB) + m][(NB) + n] = __builtin_amdgcn_mfma_i32_16x16x64_i8(     \
          AF[m], BF[n], acc[(MB) + m][(NB) + n], 0, 0, 0);                 \
  __builtin_amdgcn_s_setprio(0);

    // ---- ph1 : m0-3 x n0-1, k0 ----
#pragma unroll
    for (int m = 0; m < 4; ++m) afrA[m] = *(const i32x4*)(pA + m * 2048 + off[0]);
#pragma unroll
    for (int n = 0; n < 2; ++n) bfr0[n] = *(const i32x4*)(pB + n * 2048 + off[0]);
    if (st) STG_B(nB, 0, 0, tn);
    __builtin_amdgcn_s_barrier();
    MFMA8(afrA, bfr0, 0, 0)

    // ---- ph2 : m0-3 x n2-3, k0 ----
#pragma unroll
    for (int n = 0; n < 2; ++n) bfr1[n] = *(const i32x4*)(pB + 4096 + n * 2048 + off[0]);
    if (st) { STG_B(nB, 0, 1, tn);
              asm volatile("s_waitcnt vmcnt(2)" ::: "memory"); }  // A01,A11 of t
    else      asm volatile("s_waitcnt vmcnt(0)" ::: "memory");    // last tile
    __builtin_amdgcn_s_barrier();
    MFMA8(afrA, bfr1, 0, 2)

    // ---- ph3 : m4-7 x n0-1, k0 ----
#pragma unroll
    for (int m = 0; m < 4; ++m) afrB[m] = *(const i32x4*)(pA + 8192 + m * 2048 + off[0]);
    if (st) STG_B(nB, 1, 0, tn);
    __builtin_amdgcn_s_barrier();
    MFMA8(afrB, bfr0, 4, 0)

    // ---- ph4 : m4-7 x n2-3, k0 ----
    if (st) STG_B(nB, 1, 1, tn);
    __builtin_amdgcn_s_barrier();
    MFMA8(afrB, bfr1, 4, 2)

    // ---- ph5 : m0-3 x n0-1, k1 ----
#pragma unroll
    for (int m = 0; m < 4; ++m) afrA[m] = *(const i32x4*)(pA + m * 2048 + off[1]);
#pragma unroll
    for (int n = 0; n < 2; ++n) bfr0[n] = *(const i32x4*)(pB + n * 2048 + off[1]);
    if (st) STG_A(nA, 0, 0, tn);
    __builtin_amdgcn_s_barrier();
    MFMA8(afrA, bfr0, 0, 0)

    // ---- ph6 : m0-3 x n2-3, k1 ----
#pragma unroll
    for (int n = 0; n < 2; ++n) bfr1[n] = *(const i32x4*)(pB + 4096 + n * 2048 + off[1]);
    if (st) STG_A(nA, 1, 0, tn);
    __builtin_amdgcn_s_barrier();
    MFMA8(afrA, bfr1, 0, 2)

    // ---- ph7 : m4-7 x n0-1, k1 ----
#pragma unroll
    for (int m = 0; m < 4; ++m) afrB[m] = *(const i32x4*)(pA + 8192 + m * 2048 + off[1]);
    if (st) STG_A(nA, 0, 1, tn);
    __builtin_amdgcn_s_barrier();
    MFMA8(afrB, bfr0, 4, 0)

    // ---- ph8 : m4-7 x n2-3, k1 ----
    if (st) { STG_A(nA, 1, 1, tn);
              asm volatile("s_waitcnt vmcnt(2)" ::: "memory"); }  // t+1: B*4+A00,A10
    __builtin_amdgcn_s_barrier();
    MFMA8(afrB, bfr1, 4, 2)
#undef MFMA8
  }
#undef STG_A
#undef STG_B

  // ---------- epilogue ----------
  const float scale = *scale_p;
  const float zp    = *zp_p;
  // C/D layout: col = lane&15, row = quad*4 + reg (dtype-independent)
#pragma unroll
  for (int i = 0; i < 8; ++i) {
    const int gm0 = bm + wr * 128 + i * 16 + quad * 4;
    float am[4], cm[4];
#pragma unroll
    for (int r = 0; r < 4; ++r) {
      am[r] = scale * sx[gm0 + r];
      cm[r] = -am[r] * zp * si[gm0 + r];
    }
#pragma unroll
    for (int j = 0; j < 4; ++j) {
      const int gn = bn + wc * 64 + j * 16 + lr;
      const float bb = bias[gn];
#pragma unroll
      for (int r = 0; r < 4; ++r)
        out[(size_t)(gm0 + r) * N_DIM + gn] =
            am[r] * (float)acc[i][j][r] + cm[r] + bb;
    }
  }
}

extern "C" void kernel_launch(void* const* d_in, const int* in_sizes, int n_in,
                              void* d_out, int out_size, void* d_ws, size_t ws_size,
                              hipStream_t stream) {
  const float* x     = (const float*)d_in[0];
  const int*   wq    = (const int*)d_in[1];
  const float* scale = (const float*)d_in[2];
  const float* zp    = (const float*)d_in[3];
  const float* bias  = (const float*)d_in[4];
  float* out = (float*)d_out;

  // ws: xq (8192*4096 i8) | wq8 (4096*4096 i8) | sx | si
  signed char* xq  = (signed char*)d_ws;
  signed char* wq8 = xq + (size_t)M_DIM * K_DIM;
  float* sx = (float*)(wq8 + (size_t)N_DIM * K_DIM);
  float* si = sx + M_DIM;

  prep_kernel<<<3072, 256, 0, stream>>>(x, wq, xq, wq8, sx, si);
  dim3 grid(N_DIM / 256, M_DIM / 256);  // 16 x 32
  qlinear_gemm_kernel<<<grid, 512, 0, stream>>>(xq, wq8, sx, si, scale, zp, bias, out);
}